// Round 1
// baseline (851.002 us; speedup 1.0000x reference)
//
#include <hip/hip_runtime.h>
#include <hip/hip_bf16.h>
#include <stdint.h>

typedef __attribute__((ext_vector_type(8))) short bf16x8;
typedef __attribute__((ext_vector_type(4))) float f32x4;
typedef unsigned short u16;
typedef unsigned int u32;
typedef const __attribute__((address_space(1))) u32* gp_t;
typedef __attribute__((address_space(3))) u32* lp_t;

#define HD 128
#define NH 16
#define SEQ 2048
#define PASTN 2048
#define FULLS 4096
#define DM 2048

__device__ __forceinline__ u16 f2b(float f){
  union { float f; u32 u; } v; v.f = f;
  return (u16)((v.u + 0x7fffu + ((v.u >> 16) & 1u)) >> 16);
}

// ---------------- fp32 -> bf16 convert (vectorized) ----------------
__global__ void k_conv(const float* __restrict__ src, u16* __restrict__ dst, int n4){
  int i = blockIdx.x * blockDim.x + threadIdx.x;
  int stride = gridDim.x * blockDim.x;
  for (; i < n4; i += stride){
    float4 v = ((const float4*)src)[i];
    ushort4 o = { f2b(v.x), f2b(v.y), f2b(v.z), f2b(v.w) };
    ((ushort4*)dst)[i] = o;
  }
}

// -------- past_k: fp32 copy to out k-region rows 0..2047 + bf16 to kb --------
__global__ void k_past_k(const float* __restrict__ pk, float* __restrict__ outk,
                         u16* __restrict__ kb, int n4){
  int i = blockIdx.x * blockDim.x + threadIdx.x;
  int stride = gridDim.x * blockDim.x;
  for (; i < n4; i += stride){
    int g = i * 4;
    int c = g & 127;        // d (4-aligned)
    int r = g >> 7;         // bh*PASTN + s
    int bh = r >> 11;
    int s = r & 2047;
    long dst = ((long)bh * FULLS + s) * HD + c;
    float4 v = ((const float4*)pk)[i];
    *(float4*)(outk + dst) = v;
    ushort4 o = { f2b(v.x), f2b(v.y), f2b(v.z), f2b(v.w) };
    *(ushort4*)(kb + dst) = o;
  }
}

// -------- past_v: fp32 copy + bf16 TRANSPOSED into vtb[bh][d][key] --------
__global__ void k_past_v(const float* __restrict__ pv, float* __restrict__ outv,
                         u16* __restrict__ vtb){
  __shared__ float tile[32][33];
  int bh = blockIdx.z;
  int d0 = blockIdx.x * 32;
  int s0 = blockIdx.y * 32;
  int tx = threadIdx.x, ty = threadIdx.y;
  const float* src = pv + (long)bh * PASTN * HD;
  float* dstv = outv + (long)bh * FULLS * HD;
#pragma unroll
  for (int k = 0; k < 4; k++){
    int si = ty + 8 * k;
    float v = src[(long)(s0 + si) * HD + d0 + tx];
    dstv[(long)(s0 + si) * HD + d0 + tx] = v;
    tile[si][tx] = v;
  }
  __syncthreads();
  u16* dstt = vtb + (long)bh * HD * FULLS;
#pragma unroll
  for (int k = 0; k < 4; k++){
    int di = ty + 8 * k;
    dstt[(long)(d0 + di) * FULLS + (s0 + tx)] = f2b(tile[tx][di]);
  }
}

// ---------------- bt-GEMM: C = A(MxK) * B(NxK)^T, bf16 in, modes: ----------------
// MODE 0: Q -> qb bf16 (B,H,S,HD)
// MODE 1: K -> kb bf16 rows PASTN.. AND outf fp32 (same layout)
// MODE 2: V -> vtb bf16 transposed (cols PASTN..) AND outf fp32 (B,H,FULLS,HD)
// MODE 3: O -> outf fp32 row-major MxN
template<int MODE>
__global__ void k_gemm(const u16* __restrict__ A, const u16* __restrict__ Bm,
                       float* __restrict__ outf, u16* __restrict__ outb,
                       int M, int N, int K)
{
  __shared__ u16 As[128 * 64];
  __shared__ u16 Bs[128 * 64];
  const int tid = threadIdx.x;
  const int w = tid >> 6, l = tid & 63;
  const int m0 = blockIdx.y * 128, n0 = blockIdx.x * 128;
  const int wr = w >> 1, wc = w & 1;
  const int lr = l & 15;
  const int lkb = (l >> 4) * 16;     // byte offset of this lane's k-slice (16B)
  f32x4 acc[4][4] = {};

  for (int kt = 0; kt < K; kt += 64){
#pragma unroll
    for (int it = 0; it < 4; it++){
      int Pw = it * 4096 + w * 1024;   // wave-uniform LDS byte base
      int P = Pw + l * 16;
      int row = P >> 7, cb = P & 127;
      const u16* ga = A + (long)(m0 + row) * K + kt + (cb >> 1);
      __builtin_amdgcn_global_load_lds((gp_t)(const void*)ga, (lp_t)(void*)((char*)As + Pw), 16, 0, 0);
      const u16* gb = Bm + (long)(n0 + row) * K + kt + (cb >> 1);
      __builtin_amdgcn_global_load_lds((gp_t)(const void*)gb, (lp_t)(void*)((char*)Bs + Pw), 16, 0, 0);
    }
    __syncthreads();
#pragma unroll
    for (int kk = 0; kk < 2; kk++){
      bf16x8 af[4], bf[4];
#pragma unroll
      for (int i = 0; i < 4; i++){
        af[i] = *(const bf16x8*)((const char*)As + (wr * 64 + i * 16 + lr) * 128 + kk * 64 + lkb);
        bf[i] = *(const bf16x8*)((const char*)Bs + (wc * 64 + i * 16 + lr) * 128 + kk * 64 + lkb);
      }
#pragma unroll
      for (int i = 0; i < 4; i++)
#pragma unroll
        for (int j = 0; j < 4; j++)
          acc[i][j] = __builtin_amdgcn_mfma_f32_16x16x32_bf16(af[i], bf[j], acc[i][j], 0, 0, 0);
    }
    __syncthreads();
  }

  // epilogue: row = m0+wr*64+i*16+(l>>4)*4+r ; col = n0+wc*64+j*16+lr
  const int rbase = m0 + wr * 64 + ((l >> 4) << 2);
  const int cbase = n0 + wc * 64 + lr;
#pragma unroll
  for (int i = 0; i < 4; i++){
#pragma unroll
    for (int j = 0; j < 4; j++){
      const int nn = cbase + j * 16;
      if (MODE == 2){
        // pack 4 consecutive s into one 8B store for vtb
        const int mm = rbase + i * 16;
        const int b = mm >> 11, s = mm & 2047;
        const int h = nn >> 7, dd = nn & 127;
        const int bh = b * NH + h;
        ushort4 pk = { f2b(acc[i][j][0]), f2b(acc[i][j][1]), f2b(acc[i][j][2]), f2b(acc[i][j][3]) };
        *(ushort4*)(outb + ((long)bh * HD + dd) * FULLS + PASTN + s) = pk;
#pragma unroll
        for (int r = 0; r < 4; r++){
          long idx = ((long)bh * FULLS + PASTN + s + r) * HD + dd;
          outf[idx] = acc[i][j][r];
        }
      } else {
#pragma unroll
        for (int r = 0; r < 4; r++){
          const int mm = rbase + i * 16 + r;
          float v = acc[i][j][r];
          if (MODE == 0){
            const int b = mm >> 11, s = mm & 2047;
            const int h = nn >> 7, dd = nn & 127;
            outb[(((long)(b * NH + h)) * SEQ + s) * HD + dd] = f2b(v);
          } else if (MODE == 1){
            const int b = mm >> 11, s = mm & 2047;
            const int h = nn >> 7, dd = nn & 127;
            long idx = (((long)(b * NH + h)) * FULLS + PASTN + s) * HD + dd;
            outb[idx] = f2b(v);
            outf[idx] = v;
          } else { // MODE 3
            outf[(long)mm * N + nn] = v;
          }
        }
      }
    }
  }
}

// ---------------- flash attention ----------------
// grid (SEQ/64, B*NH), block 256 (4 waves, each owns 16 q rows)
__global__ void k_attn(const u16* __restrict__ qb, const u16* __restrict__ kb,
                       const u16* __restrict__ vtb, u16* __restrict__ ab)
{
  __shared__ u16 Ks[64 * 128];       // [key][d] 16KB
  __shared__ u16 Vs[128 * 64];       // [d][key] 16KB
  __shared__ u16 Ps[4][16 * 64];     // per-wave P [q][key] 8KB
  const int tid = threadIdx.x, w = tid >> 6, l = tid & 63;
  const int bh = blockIdx.y;
  const int q0 = blockIdx.x * 64;
  const int lr = l & 15;
  const int lkb = (l >> 4) * 16;     // k-slice byte offset
  const u16* qhead = qb + (long)bh * SEQ * HD;
  const u16* khead = kb + (long)bh * FULLS * HD;
  const u16* vhead = vtb + (long)bh * HD * FULLS;

  bf16x8 qf[4];
#pragma unroll
  for (int ks = 0; ks < 4; ks++)
    qf[ks] = *(const bf16x8*)(qhead + (long)(q0 + w * 16 + lr) * HD + ks * 32 + (l >> 4) * 8);

  f32x4 acc_o[8] = {};
  float m_run[4], l_run[4];
#pragma unroll
  for (int r = 0; r < 4; r++){ m_run[r] = -1e30f; l_run[r] = 0.f; }

  const int ntiles = (PASTN + q0 + 64) >> 6;
  const float scale = 0.08838834764831845f;  // 1/sqrt(128)
  const float l2e = 1.4426950408889634f;

  for (int t = 0; t < ntiles; t++){
    // stage K tile (contiguous 16KB) and V tile (128 rows x 128B)
    const u16* ktile = khead + (long)t * 64 * HD;
#pragma unroll
    for (int it = 0; it < 4; it++){
      int Pw = it * 4096 + w * 1024;
      int P = Pw + l * 16;
      __builtin_amdgcn_global_load_lds((gp_t)(const void*)((const char*)ktile + P),
                                       (lp_t)(void*)((char*)Ks + Pw), 16, 0, 0);
      int row = P >> 7, cb = P & 127;
      const u16* gv = vhead + (long)row * FULLS + t * 64 + (cb >> 1);
      __builtin_amdgcn_global_load_lds((gp_t)(const void*)gv,
                                       (lp_t)(void*)((char*)Vs + Pw), 16, 0, 0);
    }
    __syncthreads();

    // S = Q K^T for this wave's 16 q rows x 64 keys
    f32x4 sf[4];
#pragma unroll
    for (int nf = 0; nf < 4; nf++){
      f32x4 z = {};
      sf[nf] = z;
#pragma unroll
      for (int ks = 0; ks < 4; ks++){
        bf16x8 kf = *(const bf16x8*)((const char*)Ks + (nf * 16 + lr) * 256 + ks * 64 + lkb);
        sf[nf] = __builtin_amdgcn_mfma_f32_16x16x32_bf16(qf[ks], kf, sf[nf], 0, 0, 0);
      }
    }

    const bool lastt = (t == ntiles - 1);
#pragma unroll
    for (int nf = 0; nf < 4; nf++){
#pragma unroll
      for (int r = 0; r < 4; r++){
        float s = sf[nf][r] * scale;
        if (lastt){
          int key = t * 64 + nf * 16 + lr;
          int qpos = PASTN + q0 + w * 16 + ((l >> 4) << 2) + r;
          if (key > qpos) s = -1e30f;
        }
        sf[nf][r] = s;
      }
    }

    // online softmax per q row (row = (l>>4)*4 + r, owned by 16 lanes)
#pragma unroll
    for (int r = 0; r < 4; r++){
      float mx = fmaxf(fmaxf(sf[0][r], sf[1][r]), fmaxf(sf[2][r], sf[3][r]));
      mx = fmaxf(mx, __shfl_xor(mx, 1));
      mx = fmaxf(mx, __shfl_xor(mx, 2));
      mx = fmaxf(mx, __shfl_xor(mx, 4));
      mx = fmaxf(mx, __shfl_xor(mx, 8));
      float mnew = fmaxf(m_run[r], mx);
      float corr = __builtin_exp2f((m_run[r] - mnew) * l2e);
      m_run[r] = mnew;
      float rowsum = 0.f;
#pragma unroll
      for (int nf = 0; nf < 4; nf++){
        float p = __builtin_exp2f((sf[nf][r] - mnew) * l2e);
        sf[nf][r] = p;
        rowsum += p;
      }
      rowsum += __shfl_xor(rowsum, 1);
      rowsum += __shfl_xor(rowsum, 2);
      rowsum += __shfl_xor(rowsum, 4);
      rowsum += __shfl_xor(rowsum, 8);
      l_run[r] = l_run[r] * corr + rowsum;
#pragma unroll
      for (int df = 0; df < 8; df++) acc_o[df][r] *= corr;
    }

    // P -> LDS (bf16), per-wave buffer
    u16* pw = &Ps[w][0];
#pragma unroll
    for (int nf = 0; nf < 4; nf++)
#pragma unroll
      for (int r = 0; r < 4; r++)
        pw[(((l >> 4) << 2) + r) * 64 + nf * 16 + lr] = f2b(sf[nf][r]);
    asm volatile("s_waitcnt lgkmcnt(0)" ::: "memory");

    // O += P V
#pragma unroll
    for (int ks = 0; ks < 2; ks++){
      bf16x8 pa = *(const bf16x8*)((const char*)pw + lr * 128 + ks * 64 + lkb);
#pragma unroll
      for (int df = 0; df < 8; df++){
        bf16x8 vf = *(const bf16x8*)((const char*)Vs + (df * 16 + lr) * 128 + ks * 64 + lkb);
        acc_o[df] = __builtin_amdgcn_mfma_f32_16x16x32_bf16(pa, vf, acc_o[df], 0, 0, 0);
      }
    }
    __syncthreads();
  }

  // normalize + write to ab (B,S,DM) bf16
  const int b = bh >> 4, h = bh & 15;
#pragma unroll
  for (int r = 0; r < 4; r++){
    float inv = 1.0f / l_run[r];
    int qg = q0 + w * 16 + ((l >> 4) << 2) + r;
    long rowbase = ((long)b * SEQ + qg) * DM + h * HD;
#pragma unroll
    for (int df = 0; df < 8; df++)
      ab[rowbase + df * 16 + lr] = f2b(acc_o[df][r] * inv);
  }
}

extern "C" void kernel_launch(void* const* d_in, const int* in_sizes, int n_in,
                              void* d_out, int out_size, void* d_ws, size_t ws_size,
                              hipStream_t stream) {
  const float* x      = (const float*)d_in[0];
  const float* past_k = (const float*)d_in[1];
  const float* past_v = (const float*)d_in[2];
  const float* Wq     = (const float*)d_in[3];
  const float* Wk     = (const float*)d_in[4];
  const float* Wv     = (const float*)d_in[5];
  const float* Wo     = (const float*)d_in[6];

  float* out  = (float*)d_out;
  float* outk = out + 8388608;       // B*S*DM
  float* outv = out + 25165824;      // + B*NH*FULLS*HD

  char* ws = (char*)d_ws;
  u16* wqb = (u16*)ws;                      //  8388608 B
  u16* wkb = (u16*)(ws + 8388608);
  u16* wvb = (u16*)(ws + 16777216);
  u16* wob = (u16*)(ws + 25165824);
  u16* xb  = (u16*)(ws + 33554432);         // 16777216 B
  u16* qb  = (u16*)(ws + 50331648);         // 16777216 B
  u16* kb  = (u16*)(ws + 67108864);         // 33554432 B
  u16* vtb = (u16*)(ws + 100663296);        // 33554432 B  (total 128 MiB)
  u16* ab  = xb;                            // alias: x consumed before attn writes

  k_conv<<<1024, 256, 0, stream>>>(x,  xb,  2097152);
  k_conv<<<1024, 256, 0, stream>>>(Wq, wqb, 1048576);
  k_conv<<<1024, 256, 0, stream>>>(Wk, wkb, 1048576);
  k_conv<<<1024, 256, 0, stream>>>(Wv, wvb, 1048576);
  k_conv<<<1024, 256, 0, stream>>>(Wo, wob, 1048576);
  k_past_k<<<2048, 256, 0, stream>>>(past_k, outk, kb, 2097152);
  k_past_v<<<dim3(4, 64, 32), dim3(32, 8), 0, stream>>>(past_v, outv, vtb);

  dim3 gg(16, 32);
  k_gemm<0><<<gg, 256, 0, stream>>>(xb, wqb, nullptr, qb, 4096, 2048, 2048);
  k_gemm<1><<<gg, 256, 0, stream>>>(xb, wkb, outk, kb, 4096, 2048, 2048);
  k_gemm<2><<<gg, 256, 0, stream>>>(xb, wvb, outv, vtb, 4096, 2048, 2048);

  k_attn<<<dim3(32, 32), 256, 0, stream>>>(qb, kb, vtb, ab);

  k_gemm<3><<<gg, 256, 0, stream>>>(ab, wob, out, nullptr, 4096, 2048, 2048);
}

// Round 2
// 741.410 us; speedup vs baseline: 1.1478x; 1.1478x over previous
//
#include <hip/hip_runtime.h>
#include <hip/hip_bf16.h>
#include <stdint.h>

typedef __attribute__((ext_vector_type(8))) short bf16x8;
typedef __attribute__((ext_vector_type(4))) float f32x4;
typedef unsigned short u16;
typedef unsigned int u32;
typedef const __attribute__((address_space(1))) u32* gp_t;
typedef __attribute__((address_space(3))) u32* lp_t;

#define HD 128
#define NH 16
#define SEQ 2048
#define PASTN 2048
#define FULLS 4096
#define DM 2048

__device__ __forceinline__ u16 f2b(float f){
  union { float f; u32 u; } v; v.f = f;
  return (u16)((v.u + 0x7fffu + ((v.u >> 16) & 1u)) >> 16);
}
__device__ __forceinline__ float b2f(u16 b){
  union { u32 u; float f; } v; v.u = ((u32)b) << 16;
  return v.f;
}

// ---------------- fp32 -> bf16 convert (vectorized) ----------------
__global__ void k_conv(const float* __restrict__ src, u16* __restrict__ dst, int n4){
  int i = blockIdx.x * blockDim.x + threadIdx.x;
  int stride = gridDim.x * blockDim.x;
  for (; i < n4; i += stride){
    float4 v = ((const float4*)src)[i];
    ushort4 o = { f2b(v.x), f2b(v.y), f2b(v.z), f2b(v.w) };
    ((ushort4*)dst)[i] = o;
  }
}

// -------- past_k: fp32 copy to out k-region rows 0..2047 + bf16 to kb --------
__global__ void k_past_k(const float* __restrict__ pk, float* __restrict__ outk,
                         u16* __restrict__ kb, int n4){
  int i = blockIdx.x * blockDim.x + threadIdx.x;
  int stride = gridDim.x * blockDim.x;
  for (; i < n4; i += stride){
    int g = i * 4;
    int c = g & 127;        // d (4-aligned)
    int r = g >> 7;         // bh*PASTN + s
    int bh = r >> 11;
    int s = r & 2047;
    long dst = ((long)bh * FULLS + s) * HD + c;
    float4 v = ((const float4*)pk)[i];
    *(float4*)(outk + dst) = v;
    ushort4 o = { f2b(v.x), f2b(v.y), f2b(v.z), f2b(v.w) };
    *(ushort4*)(kb + dst) = o;
  }
}

// -------- past_v: fp32 copy + bf16 TRANSPOSED into vtb[bh][d][key] --------
__global__ void k_past_v(const float* __restrict__ pv, float* __restrict__ outv,
                         u16* __restrict__ vtb){
  __shared__ float tile[32][33];
  int bh = blockIdx.z;
  int d0 = blockIdx.x * 32;
  int s0 = blockIdx.y * 32;
  int tx = threadIdx.x, ty = threadIdx.y;
  const float* src = pv + (long)bh * PASTN * HD;
  float* dstv = outv + (long)bh * FULLS * HD;
#pragma unroll
  for (int k = 0; k < 4; k++){
    int si = ty + 8 * k;
    float v = src[(long)(s0 + si) * HD + d0 + tx];
    dstv[(long)(s0 + si) * HD + d0 + tx] = v;
    tile[si][tx] = v;
  }
  __syncthreads();
  u16* dstt = vtb + (long)bh * HD * FULLS;
#pragma unroll
  for (int k = 0; k < 4; k++){
    int di = ty + 8 * k;
    dstt[(long)(d0 + di) * FULLS + (s0 + tx)] = f2b(tile[tx][di]);
  }
}

// ---------------- bt-GEMM: C = A(MxK) * B(NxK)^T, bf16 in ----------------
template<int MODE>
__global__ void k_gemm(const u16* __restrict__ A, const u16* __restrict__ Bm,
                       float* __restrict__ outf, u16* __restrict__ outb,
                       int M, int N, int K)
{
  __shared__ u16 As[128 * 64];
  __shared__ u16 Bs[128 * 64];
  const int tid = threadIdx.x;
  const int w = tid >> 6, l = tid & 63;
  const int m0 = blockIdx.y * 128, n0 = blockIdx.x * 128;
  const int wr = w >> 1, wc = w & 1;
  const int lr = l & 15;
  const int lkb = (l >> 4) * 16;
  f32x4 acc[4][4] = {};

  for (int kt = 0; kt < K; kt += 64){
#pragma unroll
    for (int it = 0; it < 4; it++){
      int Pw = it * 4096 + w * 1024;
      int P = Pw + l * 16;
      int row = P >> 7, cb = P & 127;
      const u16* ga = A + (long)(m0 + row) * K + kt + (cb >> 1);
      __builtin_amdgcn_global_load_lds((gp_t)(const void*)ga, (lp_t)(void*)((char*)As + Pw), 16, 0, 0);
      const u16* gb = Bm + (long)(n0 + row) * K + kt + (cb >> 1);
      __builtin_amdgcn_global_load_lds((gp_t)(const void*)gb, (lp_t)(void*)((char*)Bs + Pw), 16, 0, 0);
    }
    __syncthreads();
#pragma unroll
    for (int kk = 0; kk < 2; kk++){
      bf16x8 af[4], bf[4];
#pragma unroll
      for (int i = 0; i < 4; i++){
        af[i] = *(const bf16x8*)((const char*)As + (wr * 64 + i * 16 + lr) * 128 + kk * 64 + lkb);
        bf[i] = *(const bf16x8*)((const char*)Bs + (wc * 64 + i * 16 + lr) * 128 + kk * 64 + lkb);
      }
#pragma unroll
      for (int i = 0; i < 4; i++)
#pragma unroll
        for (int j = 0; j < 4; j++)
          acc[i][j] = __builtin_amdgcn_mfma_f32_16x16x32_bf16(af[i], bf[j], acc[i][j], 0, 0, 0);
    }
    __syncthreads();
  }

  const int rbase = m0 + wr * 64 + ((l >> 4) << 2);
  const int cbase = n0 + wc * 64 + lr;
#pragma unroll
  for (int i = 0; i < 4; i++){
#pragma unroll
    for (int j = 0; j < 4; j++){
      const int nn = cbase + j * 16;
      if (MODE == 2){
        const int mm = rbase + i * 16;
        const int b = mm >> 11, s = mm & 2047;
        const int h = nn >> 7, dd = nn & 127;
        const int bh = b * NH + h;
        ushort4 pk = { f2b(acc[i][j][0]), f2b(acc[i][j][1]), f2b(acc[i][j][2]), f2b(acc[i][j][3]) };
        *(ushort4*)(outb + ((long)bh * HD + dd) * FULLS + PASTN + s) = pk;
#pragma unroll
        for (int r = 0; r < 4; r++){
          long idx = ((long)bh * FULLS + PASTN + s + r) * HD + dd;
          outf[idx] = acc[i][j][r];
        }
      } else {
#pragma unroll
        for (int r = 0; r < 4; r++){
          const int mm = rbase + i * 16 + r;
          float v = acc[i][j][r];
          if (MODE == 0){
            const int b = mm >> 11, s = mm & 2047;
            const int h = nn >> 7, dd = nn & 127;
            outb[(((long)(b * NH + h)) * SEQ + s) * HD + dd] = f2b(v);
          } else if (MODE == 1){
            const int b = mm >> 11, s = mm & 2047;
            const int h = nn >> 7, dd = nn & 127;
            long idx = (((long)(b * NH + h)) * FULLS + PASTN + s) * HD + dd;
            outb[idx] = f2b(v);
            outf[idx] = v;
          } else {
            outf[(long)mm * N + nn] = v;
          }
        }
      }
    }
  }
}

// ---------------- flash attention (swizzled LDS + 2-phase prefetch) ----------------
// grid (SEQ/64, B*NH), block 256 (4 waves, each owns 16 q rows)
// LDS tiles XOR-swizzled: logical (row, colbyte) stored at row*stride + (colbyte ^ ((row&7)<<4)).
// global_load_lds writes linearly -> global SOURCE address carries the inverse swizzle (rule 21).
__global__ void k_attn(const u16* __restrict__ qb, const u16* __restrict__ kb,
                       const u16* __restrict__ vtb, u16* __restrict__ ab)
{
  __shared__ u16 Ks[2][64 * 128];    // [key][d], 256B rows, 16KB x2
  __shared__ u16 Vs[2][128 * 64];    // [d][key], 128B rows, 16KB x2
  __shared__ u16 Ps[4][16 * 64];     // per-wave P [q][key], 128B rows, 8KB
  const int tid = threadIdx.x, w = tid >> 6, l = tid & 63;
  const int bh = blockIdx.y;
  const int q0 = blockIdx.x * 64;
  const int lr = l & 15;
  const int lkb = (l >> 4) * 16;
  const int xr = (lr & 7) << 4;      // read-side swizzle for rows where row&7 == lr&7
  const u16* qhead = qb + (long)bh * SEQ * HD;
  const u16* khead = kb + (long)bh * FULLS * HD;
  const u16* vhead = vtb + (long)bh * HD * FULLS;

  // Q fragments, pre-scaled by 1/sqrt(HD) * log2(e) so scores are in log2 domain
  const float qscale = 0.08838834764831845f * 1.4426950408889634f;
  bf16x8 qf[4];
#pragma unroll
  for (int ks = 0; ks < 4; ks++){
    bf16x8 t = *(const bf16x8*)(qhead + (long)(q0 + w * 16 + lr) * HD + ks * 32 + (l >> 4) * 8);
#pragma unroll
    for (int j = 0; j < 8; j++) t[j] = (short)f2b(b2f((u16)t[j]) * qscale);
    qf[ks] = t;
  }

  f32x4 acc_o[8] = {};
  float m_run[4], l_run[4];
#pragma unroll
  for (int r = 0; r < 4; r++){ m_run[r] = -1e30f; l_run[r] = 0.f; }

  const int ntiles = (PASTN + q0 + 64) >> 6;

  auto stage = [&](int buf, int t){
    const char* ktile = (const char*)(khead + (long)t * 64 * HD);
#pragma unroll
    for (int it = 0; it < 4; it++){
      int Pw = it * 4096 + w * 1024;
      int P = Pw + l * 16;
      // K: contiguous 16KB tile; src byte carries the swizzle (bits 4-6 ^ row bits)
      int ksrc = P ^ (((P >> 8) & 7) << 4);
      __builtin_amdgcn_global_load_lds((gp_t)(const void*)(ktile + ksrc),
                                       (lp_t)(void*)((char*)Ks[buf] + Pw), 16, 0, 0);
      // V: row = d (128B rows), strided global
      int row = P >> 7;
      int cb = (P & 127) ^ ((row & 7) << 4);
      const u16* gv = vhead + (long)row * FULLS + t * 64 + (cb >> 1);
      __builtin_amdgcn_global_load_lds((gp_t)(const void*)gv,
                                       (lp_t)(void*)((char*)Vs[buf] + Pw), 16, 0, 0);
    }
  };

  stage(0, 0);
  __syncthreads();

  int cur = 0;
  for (int t = 0; t < ntiles; t++){
    if (t + 1 < ntiles) stage(cur ^ 1, t + 1);

    // S = Q K^T (log2 domain) for this wave's 16 q rows x 64 keys
    const char* Kc = (const char*)Ks[cur];
    f32x4 sf[4];
#pragma unroll
    for (int nf = 0; nf < 4; nf++){
      f32x4 z = {};
      sf[nf] = z;
#pragma unroll
      for (int ks = 0; ks < 4; ks++){
        bf16x8 kf = *(const bf16x8*)(Kc + (nf * 16 + lr) * 256 + ((ks * 64 + lkb) ^ xr));
        sf[nf] = __builtin_amdgcn_mfma_f32_16x16x32_bf16(qf[ks], kf, sf[nf], 0, 0, 0);
      }
    }

    if (t == ntiles - 1){
#pragma unroll
      for (int nf = 0; nf < 4; nf++)
#pragma unroll
        for (int r = 0; r < 4; r++){
          int key = t * 64 + nf * 16 + lr;
          int qpos = PASTN + q0 + w * 16 + ((l >> 4) << 2) + r;
          if (key > qpos) sf[nf][r] = -1e30f;
        }
    }

    // online softmax with defer-max (T13)
    float mxs[4];
    int ok = 1;
#pragma unroll
    for (int r = 0; r < 4; r++){
      float mx = fmaxf(fmaxf(sf[0][r], sf[1][r]), fmaxf(sf[2][r], sf[3][r]));
      mx = fmaxf(mx, __shfl_xor(mx, 1));
      mx = fmaxf(mx, __shfl_xor(mx, 2));
      mx = fmaxf(mx, __shfl_xor(mx, 4));
      mx = fmaxf(mx, __shfl_xor(mx, 8));
      mxs[r] = mx;
      ok &= (mx <= m_run[r] + 8.f) ? 1 : 0;
    }
    if (!__all(ok)){
#pragma unroll
      for (int r = 0; r < 4; r++){
        float mnew = fmaxf(m_run[r], mxs[r]);
        float corr = __builtin_exp2f(m_run[r] - mnew);
        m_run[r] = mnew;
        l_run[r] *= corr;
#pragma unroll
        for (int df = 0; df < 8; df++) acc_o[df][r] *= corr;
      }
    }

    u16* pw = &Ps[w][0];
    const int qr4 = (l >> 4) << 2;
#pragma unroll
    for (int r = 0; r < 4; r++){
      float rowsum = 0.f;
      const int qrow = qr4 + r;
      const int pswz = (qrow & 7) << 4;
#pragma unroll
      for (int nf = 0; nf < 4; nf++){
        float p = __builtin_exp2f(sf[nf][r] - m_run[r]);
        *(u16*)((char*)pw + qrow * 128 + (((nf * 16 + lr) * 2) ^ pswz)) = f2b(p);
        rowsum += p;
      }
      rowsum += __shfl_xor(rowsum, 1);
      rowsum += __shfl_xor(rowsum, 2);
      rowsum += __shfl_xor(rowsum, 4);
      rowsum += __shfl_xor(rowsum, 8);
      l_run[r] += rowsum;
    }
    asm volatile("s_waitcnt lgkmcnt(0)" ::: "memory");

    // O += P V
    const char* Vc = (const char*)Vs[cur];
#pragma unroll
    for (int ks = 0; ks < 2; ks++){
      bf16x8 pa = *(const bf16x8*)((const char*)pw + lr * 128 + ((ks * 64 + lkb) ^ xr));
#pragma unroll
      for (int df = 0; df < 8; df++){
        bf16x8 vf = *(const bf16x8*)(Vc + (df * 16 + lr) * 128 + ((ks * 64 + lkb) ^ xr));
        acc_o[df] = __builtin_amdgcn_mfma_f32_16x16x32_bf16(pa, vf, acc_o[df], 0, 0, 0);
      }
    }
    __syncthreads();   // drains vmcnt (stage done) + all waves done reading buf[cur]
    cur ^= 1;
  }

  // normalize + write to ab (B,S,DM) bf16
  const int b = bh >> 4, h = bh & 15;
#pragma unroll
  for (int r = 0; r < 4; r++){
    float inv = 1.0f / l_run[r];
    int qg = q0 + w * 16 + ((l >> 4) << 2) + r;
    long rowbase = ((long)b * SEQ + qg) * DM + h * HD;
#pragma unroll
    for (int df = 0; df < 8; df++)
      ab[rowbase + df * 16 + lr] = f2b(acc_o[df][r] * inv);
  }
}

extern "C" void kernel_launch(void* const* d_in, const int* in_sizes, int n_in,
                              void* d_out, int out_size, void* d_ws, size_t ws_size,
                              hipStream_t stream) {
  const float* x      = (const float*)d_in[0];
  const float* past_k = (const float*)d_in[1];
  const float* past_v = (const float*)d_in[2];
  const float* Wq     = (const float*)d_in[3];
  const float* Wk     = (const float*)d_in[4];
  const float* Wv     = (const float*)d_in[5];
  const float* Wo     = (const float*)d_in[6];

  float* out  = (float*)d_out;
  float* outk = out + 8388608;       // B*S*DM
  float* outv = out + 25165824;      // + B*NH*FULLS*HD

  char* ws = (char*)d_ws;
  u16* wqb = (u16*)ws;
  u16* wkb = (u16*)(ws + 8388608);
  u16* wvb = (u16*)(ws + 16777216);
  u16* wob = (u16*)(ws + 25165824);
  u16* xb  = (u16*)(ws + 33554432);
  u16* qb  = (u16*)(ws + 50331648);
  u16* kb  = (u16*)(ws + 67108864);
  u16* vtb = (u16*)(ws + 100663296);
  u16* ab  = xb;                     // alias: x consumed before attn writes

  k_conv<<<1024, 256, 0, stream>>>(x,  xb,  2097152);
  k_conv<<<1024, 256, 0, stream>>>(Wq, wqb, 1048576);
  k_conv<<<1024, 256, 0, stream>>>(Wk, wkb, 1048576);
  k_conv<<<1024, 256, 0, stream>>>(Wv, wvb, 1048576);
  k_conv<<<1024, 256, 0, stream>>>(Wo, wob, 1048576);
  k_past_k<<<2048, 256, 0, stream>>>(past_k, outk, kb, 2097152);
  k_past_v<<<dim3(4, 64, 32), dim3(32, 8), 0, stream>>>(past_v, outv, vtb);

  dim3 gg(16, 32);
  k_gemm<0><<<gg, 256, 0, stream>>>(xb, wqb, nullptr, qb, 4096, 2048, 2048);
  k_gemm<1><<<gg, 256, 0, stream>>>(xb, wkb, outk, kb, 4096, 2048, 2048);
  k_gemm<2><<<gg, 256, 0, stream>>>(xb, wvb, outv, vtb, 4096, 2048, 2048);

  k_attn<<<dim3(32, 32), 256, 0, stream>>>(qb, kb, vtb, ab);

  k_gemm<3><<<gg, 256, 0, stream>>>(ab, wob, out, nullptr, 4096, 2048, 2048);
}

// Round 3
// 496.490 us; speedup vs baseline: 1.7140x; 1.4933x over previous
//
#include <hip/hip_runtime.h>
#include <hip/hip_bf16.h>
#include <stdint.h>

typedef __attribute__((ext_vector_type(8))) short bf16x8;
typedef __attribute__((ext_vector_type(4))) float f32x4;
typedef __attribute__((ext_vector_type(16))) float f32x16;
typedef unsigned short u16;
typedef unsigned int u32;
typedef const __attribute__((address_space(1))) u32* gp_t;
typedef __attribute__((address_space(3))) u32* lp_t;

#define HD 128
#define NH 16
#define SEQ 2048
#define PASTN 2048
#define FULLS 4096
#define DM 2048

__device__ __forceinline__ u16 f2b(float f){
  union { float f; u32 u; } v; v.f = f;
  return (u16)((v.u + 0x7fffu + ((v.u >> 16) & 1u)) >> 16);
}
__device__ __forceinline__ float b2f(u16 b){
  union { u32 u; float f; } v; v.u = ((u32)b) << 16;
  return v.f;
}
__device__ __forceinline__ u32 cvtpk(float lo, float hi){
  u32 r; asm("v_cvt_pk_bf16_f32 %0, %1, %2" : "=v"(r) : "v"(lo), "v"(hi)); return r;
}

// ---------------- fp32 -> bf16 convert (vectorized) ----------------
__global__ void k_conv(const float* __restrict__ src, u16* __restrict__ dst, int n4){
  int i = blockIdx.x * blockDim.x + threadIdx.x;
  int stride = gridDim.x * blockDim.x;
  for (; i < n4; i += stride){
    float4 v = ((const float4*)src)[i];
    ushort4 o = { f2b(v.x), f2b(v.y), f2b(v.z), f2b(v.w) };
    ((ushort4*)dst)[i] = o;
  }
}

// -------- past_k: fp32 copy to out k-region rows 0..2047 + bf16 to kb --------
__global__ void k_past_k(const float* __restrict__ pk, float* __restrict__ outk,
                         u16* __restrict__ kb, int n4){
  int i = blockIdx.x * blockDim.x + threadIdx.x;
  int stride = gridDim.x * blockDim.x;
  for (; i < n4; i += stride){
    int g = i * 4;
    int c = g & 127;
    int r = g >> 7;
    int bh = r >> 11;
    int s = r & 2047;
    long dst = ((long)bh * FULLS + s) * HD + c;
    float4 v = ((const float4*)pk)[i];
    *(float4*)(outk + dst) = v;
    ushort4 o = { f2b(v.x), f2b(v.y), f2b(v.z), f2b(v.w) };
    *(ushort4*)(kb + dst) = o;
  }
}

// -------- past_v: fp32 copy + bf16 TRANSPOSED into vtb[bh][d][key] --------
__global__ void k_past_v(const float* __restrict__ pv, float* __restrict__ outv,
                         u16* __restrict__ vtb){
  __shared__ float tile[32][33];
  int bh = blockIdx.z;
  int d0 = blockIdx.x * 32;
  int s0 = blockIdx.y * 32;
  int tx = threadIdx.x, ty = threadIdx.y;
  const float* src = pv + (long)bh * PASTN * HD;
  float* dstv = outv + (long)bh * FULLS * HD;
#pragma unroll
  for (int k = 0; k < 4; k++){
    int si = ty + 8 * k;
    float v = src[(long)(s0 + si) * HD + d0 + tx];
    dstv[(long)(s0 + si) * HD + d0 + tx] = v;
    tile[si][tx] = v;
  }
  __syncthreads();
  u16* dstt = vtb + (long)bh * HD * FULLS;
#pragma unroll
  for (int k = 0; k < 4; k++){
    int di = ty + 8 * k;
    dstt[(long)(d0 + di) * FULLS + (s0 + tx)] = f2b(tile[tx][di]);
  }
}

// ---------------- bt-GEMM: C = A(MxK) * B(NxK)^T, bf16 in ----------------
template<int MODE>
__global__ void k_gemm(const u16* __restrict__ A, const u16* __restrict__ Bm,
                       float* __restrict__ outf, u16* __restrict__ outb,
                       int M, int N, int K)
{
  __shared__ u16 As[128 * 64];
  __shared__ u16 Bs[128 * 64];
  const int tid = threadIdx.x;
  const int w = tid >> 6, l = tid & 63;
  const int m0 = blockIdx.y * 128, n0 = blockIdx.x * 128;
  const int wr = w >> 1, wc = w & 1;
  const int lr = l & 15;
  const int lkb = (l >> 4) * 16;
  f32x4 acc[4][4] = {};

  for (int kt = 0; kt < K; kt += 64){
#pragma unroll
    for (int it = 0; it < 4; it++){
      int Pw = it * 4096 + w * 1024;
      int P = Pw + l * 16;
      int row = P >> 7, cb = P & 127;
      const u16* ga = A + (long)(m0 + row) * K + kt + (cb >> 1);
      __builtin_amdgcn_global_load_lds((gp_t)(const void*)ga, (lp_t)(void*)((char*)As + Pw), 16, 0, 0);
      const u16* gb = Bm + (long)(n0 + row) * K + kt + (cb >> 1);
      __builtin_amdgcn_global_load_lds((gp_t)(const void*)gb, (lp_t)(void*)((char*)Bs + Pw), 16, 0, 0);
    }
    __syncthreads();
#pragma unroll
    for (int kk = 0; kk < 2; kk++){
      bf16x8 af[4], bf[4];
#pragma unroll
      for (int i = 0; i < 4; i++){
        af[i] = *(const bf16x8*)((const char*)As + (wr * 64 + i * 16 + lr) * 128 + kk * 64 + lkb);
        bf[i] = *(const bf16x8*)((const char*)Bs + (wc * 64 + i * 16 + lr) * 128 + kk * 64 + lkb);
      }
#pragma unroll
      for (int i = 0; i < 4; i++)
#pragma unroll
        for (int j = 0; j < 4; j++)
          acc[i][j] = __builtin_amdgcn_mfma_f32_16x16x32_bf16(af[i], bf[j], acc[i][j], 0, 0, 0);
    }
    __syncthreads();
  }

  const int rbase = m0 + wr * 64 + ((l >> 4) << 2);
  const int cbase = n0 + wc * 64 + lr;
#pragma unroll
  for (int i = 0; i < 4; i++){
#pragma unroll
    for (int j = 0; j < 4; j++){
      const int nn = cbase + j * 16;
      if (MODE == 2){
        const int mm = rbase + i * 16;
        const int b = mm >> 11, s = mm & 2047;
        const int h = nn >> 7, dd = nn & 127;
        const int bh = b * NH + h;
        ushort4 pk = { f2b(acc[i][j][0]), f2b(acc[i][j][1]), f2b(acc[i][j][2]), f2b(acc[i][j][3]) };
        *(ushort4*)(outb + ((long)bh * HD + dd) * FULLS + PASTN + s) = pk;
#pragma unroll
        for (int r = 0; r < 4; r++){
          long idx = ((long)bh * FULLS + PASTN + s + r) * HD + dd;
          outf[idx] = acc[i][j][r];
        }
      } else {
#pragma unroll
        for (int r = 0; r < 4; r++){
          const int mm = rbase + i * 16 + r;
          float v = acc[i][j][r];
          if (MODE == 0){
            const int b = mm >> 11, s = mm & 2047;
            const int h = nn >> 7, dd = nn & 127;
            outb[(((long)(b * NH + h)) * SEQ + s) * HD + dd] = f2b(v);
          } else if (MODE == 1){
            const int b = mm >> 11, s = mm & 2047;
            const int h = nn >> 7, dd = nn & 127;
            long idx = (((long)(b * NH + h)) * FULLS + PASTN + s) * HD + dd;
            outb[idx] = f2b(v);
            outf[idx] = v;
          } else {
            outf[(long)mm * N + nn] = v;
          }
        }
      }
    }
  }
}

// ------- flash attention: 4 waves x 32 q-rows, 32x32x16 MFMA, swapped QK^T,
// ------- in-register softmax (no P LDS), KV double-buffered swizzled LDS.
__global__ __launch_bounds__(256, 2)
void k_attn(const u16* __restrict__ qb, const u16* __restrict__ kb,
            const u16* __restrict__ vtb, u16* __restrict__ ab)
{
  __shared__ u16 Ks[2][64 * 128];    // [key][d] 256B rows, 16-slot swizzle
  __shared__ u16 Vs[2][128 * 64];    // [d][key] 128B rows, 8-slot swizzle
  const int tid = threadIdx.x, w = tid >> 6, l = tid & 63;
  const int lq = l & 31, hi = l >> 5;
  const int bh = blockIdx.y;
  const int q0b = blockIdx.x * 128;
  const int qbase = q0b + w * 32;
  const int qpos = PASTN + qbase + lq;     // this lane's query position
  const u16* qhead = qb + (long)bh * SEQ * HD;
  const u16* khead = kb + (long)bh * FULLS * HD;
  const u16* vhead = vtb + (long)bh * HD * FULLS;

  // Q (B-operand) fragments, prescaled by 1/sqrt(HD)*log2(e): lane holds
  // Q[q=lq][k = ks*16 + hi*8 .. +8]
  const float qscale = 0.08838834764831845f * 1.4426950408889634f;
  bf16x8 qf[8];
#pragma unroll
  for (int ks = 0; ks < 8; ks++){
    bf16x8 tq = *(const bf16x8*)(qhead + (long)(qbase + lq) * HD + ks * 16 + hi * 8);
#pragma unroll
    for (int j = 0; j < 8; j++) tq[j] = (short)f2b(b2f((u16)tq[j]) * qscale);
    qf[ks] = tq;
  }

  f32x16 acc[4] = {};                 // O[q_local(r)][d2*32+lq]
  float m_run = -1e30f, l_run = 0.f;  // stats for q = lq (both halves identical)

  const int ntiles = (PASTN + q0b + 128) >> 6;
  const int qmaxw = PASTN + qbase + 31;

  auto stage = [&](int buf, int t){
    const char* ktile = (const char*)(khead + (long)t * 64 * HD);
#pragma unroll
    for (int it = 0; it < 4; it++){
      int base = it * 4096 + w * 1024;
      int P = base + l * 16;
      // K: 256B rows, 16-slot XOR swizzle carried by the global source addr
      int ksrc = P ^ (((P >> 8) & 15) << 4);
      __builtin_amdgcn_global_load_lds((gp_t)(const void*)(ktile + ksrc),
                                       (lp_t)(void*)((char*)Ks[buf] + base), 16, 0, 0);
      // V: 128B rows (row=d), 8-slot swizzle
      int row = P >> 7;
      int cb = (P & 127) ^ ((row & 7) << 4);
      const u16* gv = vhead + (long)row * FULLS + t * 64 + (cb >> 1);
      __builtin_amdgcn_global_load_lds((gp_t)(const void*)gv,
                                       (lp_t)(void*)((char*)Vs[buf] + base), 16, 0, 0);
    }
  };

  stage(0, 0);
  __syncthreads();

  int cur = 0;
  for (int t = 0; t < ntiles; t++){
    if (t + 1 < ntiles) stage(cur ^ 1, t + 1);
    const int kvb = t * 64;
    if (kvb <= qmaxw){               // wave-uniform: any of this wave's rows attends
      // ---- S^T = K Q : lane holds S[key = kvb + kb2*32 + (r&3)+8*(r>>2)+4*hi][q=lq]
      const char* Kc = (const char*)Ks[cur];
      f32x16 s0 = {}, s1 = {};
      const int kswz = (lq & 15) << 4;
#pragma unroll
      for (int ks = 0; ks < 8; ks++){
        int c = ks * 32 + hi * 16;
        bf16x8 kf0 = *(const bf16x8*)(Kc + lq * 256 + (c ^ kswz));
        bf16x8 kf1 = *(const bf16x8*)(Kc + (32 + lq) * 256 + (c ^ kswz));
        s0 = __builtin_amdgcn_mfma_f32_32x32x16_bf16(kf0, qf[ks], s0, 0, 0, 0);
        s1 = __builtin_amdgcn_mfma_f32_32x32x16_bf16(kf1, qf[ks], s1, 0, 0, 0);
      }

      // ---- causal mask (log2-domain scores)
      if (kvb + 63 > PASTN + qbase){
#pragma unroll
        for (int r = 0; r < 16; r++){
          int key = kvb + (r & 3) + 8 * (r >> 2) + 4 * hi;
          if (key > qpos) s0[r] = -1e30f;
          if (key + 32 > qpos) s1[r] = -1e30f;
        }
      }

      // ---- in-register row max (31 fmax + 1 cross-half shuffle)
      float a0[8];
#pragma unroll
      for (int i = 0; i < 8; i++)
        a0[i] = fmaxf(fmaxf(s0[i], s0[i + 8]), fmaxf(s1[i], s1[i + 8]));
      float a1[4];
#pragma unroll
      for (int i = 0; i < 4; i++) a1[i] = fmaxf(a0[i], a0[i + 4]);
      float mx = fmaxf(fmaxf(a1[0], a1[1]), fmaxf(a1[2], a1[3]));
      mx = fmaxf(mx, __shfl_xor(mx, 32));

      // ---- defer-max rescale (rare)
      if (!__all(mx <= m_run + 8.f)){
        float mnew = fmaxf(m_run, mx);
        float corr = __builtin_exp2f(m_run - mnew);
        m_run = mnew; l_run *= corr;
#pragma unroll
        for (int r = 0; r < 16; r++){
          int qlr = (r & 3) + 8 * (r >> 2) + 4 * hi;
          float cr = __shfl(corr, qlr);
#pragma unroll
          for (int d2 = 0; d2 < 4; d2++) acc[d2][r] *= cr;
        }
      }

      // ---- P = exp2(S - m), row sum
      float rs = 0.f;
#pragma unroll
      for (int r = 0; r < 16; r++){
        s0[r] = __builtin_exp2f(s0[r] - m_run); rs += s0[r];
        s1[r] = __builtin_exp2f(s1[r] - m_run); rs += s1[r];
      }
      rs += __shfl_xor(rs, 32);
      l_run += rs;

      // ---- pack P into A-fragments: lane needs P[q=lq][k = ks2*16 + hi*8 ..+8]
      bf16x8 pfrag[4];
#pragma unroll
      for (int kb2 = 0; kb2 < 2; kb2++){
        f32x16 sp = kb2 ? s1 : s0;
#pragma unroll
        for (int half = 0; half < 2; half++){
          float p0 = sp[half * 8 + 0], p1 = sp[half * 8 + 1];
          float p2 = sp[half * 8 + 2], p3 = sp[half * 8 + 3];
          float p4 = sp[half * 8 + 4], p5 = sp[half * 8 + 5];
          float p6 = sp[half * 8 + 6], p7 = sp[half * 8 + 7];
          u32 x0 = cvtpk(p0, p1), x1 = cvtpk(p2, p3);
          u32 y0 = cvtpk(p4, p5), y1 = cvtpk(p6, p7);
          u32 sx0 = (u32)__shfl_xor((int)x0, 32);
          u32 sx1 = (u32)__shfl_xor((int)x1, 32);
          u32 sy0 = (u32)__shfl_xor((int)y0, 32);
          u32 sy1 = (u32)__shfl_xor((int)y1, 32);
          union { u32 wd[4]; bf16x8 v; } F;
          F.wd[0] = hi ? sy0 : x0;
          F.wd[1] = hi ? sy1 : x1;
          F.wd[2] = hi ? y0 : sx0;
          F.wd[3] = hi ? y1 : sx1;
          pfrag[kb2 * 2 + half] = F.v;
        }
      }

      // ---- O += P V
      const char* Vc = (const char*)Vs[cur];
#pragma unroll
      for (int ks2 = 0; ks2 < 4; ks2++){
        int c = ks2 * 32 + hi * 16;
#pragma unroll
        for (int d2 = 0; d2 < 4; d2++){
          int row = d2 * 32 + lq;
          bf16x8 vf = *(const bf16x8*)(Vc + row * 128 + (c ^ ((row & 7) << 4)));
          acc[d2] = __builtin_amdgcn_mfma_f32_32x32x16_bf16(pfrag[ks2], vf, acc[d2], 0, 0, 0);
        }
      }
    }
    __syncthreads();
    cur ^= 1;
  }

  // ---- epilogue: normalize, write ab (B,S,DM) bf16
  float inv = 1.0f / l_run;
  const int b = bh >> 4, h = bh & 15;
#pragma unroll
  for (int r = 0; r < 16; r++){
    int qlr = (r & 3) + 8 * (r >> 2) + 4 * hi;
    float ir = __shfl(inv, qlr);
    long rowbase = ((long)b * SEQ + (qbase + qlr)) * DM + h * HD;
#pragma unroll
    for (int d2 = 0; d2 < 4; d2++)
      ab[rowbase + d2 * 32 + lq] = f2b(acc[d2][r] * ir);
  }
}

extern "C" void kernel_launch(void* const* d_in, const int* in_sizes, int n_in,
                              void* d_out, int out_size, void* d_ws, size_t ws_size,
                              hipStream_t stream) {
  const float* x      = (const float*)d_in[0];
  const float* past_k = (const float*)d_in[1];
  const float* past_v = (const float*)d_in[2];
  const float* Wq     = (const float*)d_in[3];
  const float* Wk     = (const float*)d_in[4];
  const float* Wv     = (const float*)d_in[5];
  const float* Wo     = (const float*)d_in[6];

  float* out  = (float*)d_out;
  float* outk = out + 8388608;       // B*S*DM
  float* outv = out + 25165824;      // + B*NH*FULLS*HD

  char* ws = (char*)d_ws;
  u16* wqb = (u16*)ws;
  u16* wkb = (u16*)(ws + 8388608);
  u16* wvb = (u16*)(ws + 16777216);
  u16* wob = (u16*)(ws + 25165824);
  u16* xb  = (u16*)(ws + 33554432);
  u16* qb  = (u16*)(ws + 50331648);
  u16* kb  = (u16*)(ws + 67108864);
  u16* vtb = (u16*)(ws + 100663296);
  u16* ab  = xb;                     // alias: x consumed before attn writes

  k_conv<<<1024, 256, 0, stream>>>(x,  xb,  2097152);
  k_conv<<<1024, 256, 0, stream>>>(Wq, wqb, 1048576);
  k_conv<<<1024, 256, 0, stream>>>(Wk, wkb, 1048576);
  k_conv<<<1024, 256, 0, stream>>>(Wv, wvb, 1048576);
  k_conv<<<1024, 256, 0, stream>>>(Wo, wob, 1048576);
  k_past_k<<<2048, 256, 0, stream>>>(past_k, outk, kb, 2097152);
  k_past_v<<<dim3(4, 64, 32), dim3(32, 8), 0, stream>>>(past_v, outv, vtb);

  dim3 gg(16, 32);
  k_gemm<0><<<gg, 256, 0, stream>>>(xb, wqb, nullptr, qb, 4096, 2048, 2048);
  k_gemm<1><<<gg, 256, 0, stream>>>(xb, wkb, outk, kb, 4096, 2048, 2048);
  k_gemm<2><<<gg, 256, 0, stream>>>(xb, wvb, outv, vtb, 4096, 2048, 2048);

  k_attn<<<dim3(16, 32), 256, 0, stream>>>(qb, kb, vtb, ab);

  k_gemm<3><<<gg, 256, 0, stream>>>(ab, wob, out, nullptr, 4096, 2048, 2048);
}